// Round 8
// baseline (581.213 us; speedup 1.0000x reference)
//
#include <hip/hip_runtime.h>
#include <stdint.h>

// Problem: x (8,4096,512) f32 -> NQ=32768 rows; codebook (4096,512) f32.
// Outputs f32 concat: q_st[NQ*D], commitment[NQ], cbn[M*D]
//
// v8: screen = v5 geometry (512thr, 128q/block, grid 256, 128KB LDS) +
// DEFERRED top-3: reduce tile ct-1's accumulators while tile ct's MFMAs run
// (T15: prev values are retired -> VALU fills MFMA stalls; v5/v7 reduced the
// JUST-ISSUED accs, serializing VALU after the MFMA chain every tile).
// Tail identical to v7 (TAU3 gate + block-reduced scan atomics).
#define NQ 32768
#define D  512
#define M  4096
#define TAU  5e-4f
#define TAU3 1.5e-4f

typedef _Float16 f16x8 __attribute__((ext_vector_type(8)));
typedef _Float16 f16x4 __attribute__((ext_vector_type(4)));
typedef float    f32x16 __attribute__((ext_vector_type(16)));

#define Z16 ((f32x16){0.f,0.f,0.f,0.f,0.f,0.f,0.f,0.f,0.f,0.f,0.f,0.f,0.f,0.f,0.f,0.f})

__device__ __forceinline__ void gl2lds16(const void* g, void* l) {
    __builtin_amdgcn_global_load_lds(
        (const __attribute__((address_space(1))) unsigned int*)g,
        (__attribute__((address_space(3))) unsigned int*)l,
        16, 0, 0);
}

// ---------------- Kernel: fused x-prep + codebook row norms ---------------
__global__ void k_prep(const float* __restrict__ x, const float* __restrict__ cb,
                       float* __restrict__ invn, _Float16* __restrict__ xh,
                       float* __restrict__ invcb, int* __restrict__ counter) {
    int wv = threadIdx.x >> 6, lane = threadIdx.x & 63;
    if (blockIdx.x < NQ / 4) {
        int row = blockIdx.x * 4 + wv;
        const float4* src = (const float4*)(x + (size_t)row * D);
        float4 a = src[lane];
        float4 b = src[lane + 64];
        float ss = a.x*a.x + a.y*a.y + a.z*a.z + a.w*a.w
                 + b.x*b.x + b.y*b.y + b.z*b.z + b.w*b.w;
        #pragma unroll
        for (int o = 32; o > 0; o >>= 1) ss += __shfl_xor(ss, o, 64);
        float iv = 1.0f / fmaxf(sqrtf(ss), 1e-12f);
        if (lane == 0) invn[row] = iv;
        f16x4 ha = { (_Float16)(a.x*iv), (_Float16)(a.y*iv),
                     (_Float16)(a.z*iv), (_Float16)(a.w*iv) };
        f16x4 hb = { (_Float16)(b.x*iv), (_Float16)(b.y*iv),
                     (_Float16)(b.z*iv), (_Float16)(b.w*iv) };
        *(f16x4*)(xh + (size_t)row * D + lane * 4)       = ha;
        *(f16x4*)(xh + (size_t)row * D + 256 + lane * 4) = hb;
    } else {
        if (blockIdx.x == NQ / 4 && threadIdx.x == 0) *counter = 0;
        int row = (blockIdx.x - NQ / 4) * 4 + wv;
        const float4* src = (const float4*)(cb + (size_t)row * D);
        float4 a = src[lane];
        float4 b = src[lane + 64];
        float ss = a.x*a.x + a.y*a.y + a.z*a.z + a.w*a.w
                 + b.x*b.x + b.y*b.y + b.z*b.z + b.w*b.w;
        #pragma unroll
        for (int o = 32; o > 0; o >>= 1) ss += __shfl_xor(ss, o, 64);
        if (lane == 0) invcb[row] = 1.0f / fmaxf(sqrtf(ss), 1e-12f);
    }
}

// ---------------- Kernel: normalize + retile codebook ---------------------
__global__ void k_tile_cb2(const float* __restrict__ cb,
                           const float* __restrict__ invcb,
                           float* __restrict__ cbn,
                           _Float16* __restrict__ slab) {
    int ct = blockIdx.x >> 2, kc = blockIdx.x & 3;   // kc = K-128 quarter
    __shared__ float xs[64 * 129];
    int tid = threadIdx.x;
    #pragma unroll
    for (int pass = 0; pass < 8; pass++) {
        int row = pass * 8 + (tid >> 5);
        int col = (tid & 31) * 4;
        size_t goff = (size_t)(ct * 64 + row) * D + kc * 128 + col;
        float4 v = *(const float4*)(cb + goff);
        float sc = invcb[ct * 64 + row];
        v.x *= sc; v.y *= sc; v.z *= sc; v.w *= sc;
        *(float4*)(cbn + goff) = v;
        xs[row * 129 + col + 0] = v.x;
        xs[row * 129 + col + 1] = v.y;
        xs[row * 129 + col + 2] = v.z;
        xs[row * 129 + col + 3] = v.w;
    }
    __syncthreads();
    #pragma unroll
    for (int i = 0; i < 4; i++) {
        int cid = i * 256 + tid;
        int tt = cid >> 6, m = cid & 63;            // tt: local k-chunk 0..15
        size_t id = (((size_t)ct * 2 + (kc >> 1)) * 32 + (kc & 1) * 16 + tt) * 64 + m;
        f16x8 v;
        #pragma unroll
        for (int j = 0; j < 8; j++) v[j] = (_Float16)xs[m * 129 + tt * 8 + j];
        *(f16x8*)(slab + id * 8) = v;
    }
}

// ---------------- top-3 merge of two sorted triples (idx tiebreak top-2) ---
__device__ __forceinline__ void merge3(float& s1, float& s2, float& s3,
                                       int& i1, int& i2,
                                       float o1, float o2, float o3,
                                       int oi1, int oi2) {
    bool bA = (o1 > s1) || (o1 == s1 && oi1 < i1);
    float m1 = bA ? o1 : s1; int m1i = bA ? oi1 : i1;
    float hAv = bA ? s1 : s2; int hAi = bA ? i1 : i2;
    float hBv = bA ? o2 : o1; int hBi = bA ? oi2 : oi1;
    bool bB = (hBv > hAv) || (hBv == hAv && hBi < hAi);
    float m2 = bB ? hBv : hAv; int m2i = bB ? hBi : hAi;
    float nAv = bA ? s2 : s3;
    float nBv = bA ? o3 : o2;
    float m3 = bB ? fmaxf(hAv, nBv) : fmaxf(hBv, nAv);
    s1 = m1; s2 = m2; s3 = m3; i1 = m1i; i2 = m2i;
}

__device__ __forceinline__ void top3_upd(float v, int ci,
                                         float& s1, float& s2, float& s3,
                                         int& i1, int& i2) {
    bool b1 = v > s1, b2 = v > s2, b3 = v > s3;
    s3 = b2 ? s2 : (b3 ? v : s3);
    s2 = b1 ? s1 : (b2 ? v : s2);
    i2 = b1 ? i1 : (b2 ? ci : i2);
    s1 = b1 ? v : s1;
    i1 = b1 ? ci : i1;
}

// ---------------- Kernel: fp16 32x32x16 screen, top-3, deferred reduce -----
// 512 thr = 8 waves: 4 query-groups (32 q, xf pinned) x 2 code-halves.
// Per tile ct (64 codes x K512 = 2 phases): MFMAs accumulate into the CURRENT
// acc set while the PREVIOUS tile's acc set is top-3-reduced (values already
// retired -> VALU overlaps MFMA). Explicit A/B ping-pong, static indexing.
__launch_bounds__(512, 2)
__global__ void k_screen_h(const _Float16* __restrict__ xh_g,
                           const _Float16* __restrict__ slab,
                           float* __restrict__ marg, float* __restrict__ marg3,
                           int* __restrict__ bidx_g, int* __restrict__ bidx2_g) {
    __shared__ f16x8 lbuf[2][2][2048];     // [half][dbuf][t*64+m], 128 KB
    __shared__ float ms1[8][32], ms2[8][32], ms3[8][32];
    __shared__ int   mi1[8][32], mi2[8][32];

    int tid = threadIdx.x;
    int lane = tid & 63, w = tid >> 6;
    int half = w >> 2;                      // code half (0: codes 0..2047)
    int qg = w & 3;                         // query group within block
    int l31 = lane & 31, hi = lane >> 5;
    int q = blockIdx.x * 128 + qg * 32 + l31;
    int wl = w & 3;                         // wave index within half

    // pin x fragments: B-frag for 32x32x16: [n=lane&31][k=(lane>>5)*8+j]
    f16x8 xf[32];
    {
        const _Float16* xr = xh_g + (size_t)q * D + hi * 8;
        #pragma unroll
        for (int i = 0; i < 32; i++) xf[i] = *(const f16x8*)(xr + i * 16);
    }

    float s1 = -1e30f, s2 = -1e30f, s3 = -1e30f;
    int i1 = 0, i2 = 0;

    const char* slab_b = (const char*)slab;

#define STAGE(GSTEP, BUF) do {                                                 \
        const char* sb_ = slab_b + ((size_t)(GSTEP) * 2048 + lane) * 16;       \
        _Pragma("unroll")                                                      \
        for (int i_ = 0; i_ < 8; i_++) {                                       \
            int s_ = wl * 8 + i_;                                              \
            gl2lds16(sb_ + (size_t)s_ * 1024,                                  \
                     (char*)&lbuf[half][BUF][0] + s_ * 1024);                  \
        }                                                                      \
    } while (0)

// One phase (K-half 256 of one 64-code tile): barrier, stage next, 32 MFMA
// into (A0,A1); if RED, top-3 reduce 16 values of the PREVIOUS tile's PV
// (ci base PCB), then zero PV for reuse.
#define PHASE(LS, XB, A0, A1, RED, PV, PCB) do {                               \
        __syncthreads();                                                       \
        if ((LS) + 1 < 64) STAGE(pbase + (LS) + 1, ((LS) + 1) & 1);            \
        {                                                                      \
            const f16x8* bufp_ = &lbuf[half][(LS) & 1][0];                     \
            __builtin_amdgcn_s_setprio(1);                                     \
            _Pragma("unroll")                                                  \
            for (int s_ = 0; s_ < 16; s_++) {                                  \
                int cb_ = (s_ * 2 + hi) * 64 + l31;                            \
                f16x8 a0_ = bufp_[cb_];                                        \
                f16x8 a1_ = bufp_[cb_ + 32];                                   \
                A0 = __builtin_amdgcn_mfma_f32_32x32x16_f16(a0_, xf[(XB) + s_], A0, 0, 0, 0); \
                A1 = __builtin_amdgcn_mfma_f32_32x32x16_f16(a1_, xf[(XB) + s_], A1, 0, 0, 0); \
            }                                                                  \
            __builtin_amdgcn_s_setprio(0);                                     \
        }                                                                      \
        if (RED) {                                                             \
            _Pragma("unroll")                                                  \
            for (int r_ = 0; r_ < 16; r_++) {                                  \
                float v_ = (PV)[r_];                                           \
                int ci_ = (PCB) + (r_ & 3) + 8 * (r_ >> 2) + 4 * hi;           \
                top3_upd(v_, ci_, s1, s2, s3, i1, i2);                         \
            }                                                                  \
            PV = Z16;                                                          \
        }                                                                      \
    } while (0)

    int pbase = half * 64;                  // this half's gstep range
    STAGE(pbase, 0);

    f32x16 aA0 = Z16, aA1 = Z16, aB0 = Z16, aB1 = Z16;

    // tile 0 -> A (nothing to reduce yet)
    PHASE(0, 0,  aA0, aA1, false, aA0, 0);
    PHASE(1, 16, aA0, aA1, false, aA0, 0);

    for (int ctp = 0; ctp < 15; ctp++) {
        int ctB = 2 * ctp + 1;              // compute B, reduce A (tile ctB-1)
        int bB = (half * 32 + ctB - 1) * 64;
        PHASE(2 * ctB,     0,  aB0, aB1, true, aA0, bB);
        PHASE(2 * ctB + 1, 16, aB0, aB1, true, aA1, bB + 32);
        int ctA = 2 * ctp + 2;              // compute A, reduce B (tile ctA-1)
        int bA = (half * 32 + ctA - 1) * 64;
        PHASE(2 * ctA,     0,  aA0, aA1, true, aB0, bA);
        PHASE(2 * ctA + 1, 16, aA0, aA1, true, aB1, bA + 32);
    }
    {   // tile 31 -> B, reduce A (tile 30)
        int bB = (half * 32 + 30) * 64;
        PHASE(62, 0,  aB0, aB1, true, aA0, bB);
        PHASE(63, 16, aB0, aB1, true, aA1, bB + 32);
    }
    {   // epilogue: reduce tile 31 (in B)
        int cb31 = (half * 32 + 31) * 64;
        #pragma unroll
        for (int r = 0; r < 16; r++)
            top3_upd(aB0[r], cb31 + (r & 3) + 8 * (r >> 2) + 4 * hi,
                     s1, s2, s3, i1, i2);
        #pragma unroll
        for (int r = 0; r < 16; r++)
            top3_upd(aB1[r], cb31 + 32 + (r & 3) + 8 * (r >> 2) + 4 * hi,
                     s1, s2, s3, i1, i2);
    }
#undef PHASE
#undef STAGE

    // merge the two lanes holding the same query (lane ^ 32)
    {
        float o1 = __shfl_xor(s1, 32, 64);
        float o2 = __shfl_xor(s2, 32, 64);
        float o3 = __shfl_xor(s3, 32, 64);
        int oi1 = __shfl_xor(i1, 32, 64);
        int oi2 = __shfl_xor(i2, 32, 64);
        merge3(s1, s2, s3, i1, i2, o1, o2, o3, oi1, oi2);
    }
    if (hi == 0) {
        ms1[w][l31] = s1; ms2[w][l31] = s2; ms3[w][l31] = s3;
        mi1[w][l31] = i1; mi2[w][l31] = i2;
    }
    __syncthreads();
    // merge the two code-halves (waves w and w+4 share a query group)
    if (half == 0 && hi == 0) {
        merge3(s1, s2, s3, i1, i2,
               ms1[w + 4][l31], ms2[w + 4][l31], ms3[w + 4][l31],
               mi1[w + 4][l31], mi2[w + 4][l31]);
        marg[q]    = s1 - s2;
        marg3[q]   = s1 - s3;
        bidx_g[q]  = i1;
        bidx2_g[q] = i2;
    }
}

// ---------------- Kernel: gather + commitment, always-exact dot ------------
__global__ void k_write_fix2(const float* __restrict__ x, const float* __restrict__ invn,
                             const float* __restrict__ cbn,
                             const float* __restrict__ marg, const float* __restrict__ marg3,
                             const int* __restrict__ idx1, const int* __restrict__ idx2,
                             float* __restrict__ outq, float* __restrict__ outc,
                             int* __restrict__ counter, int* __restrict__ list,
                             unsigned long long* __restrict__ pk) {
    int wave = threadIdx.x >> 6, lane = threadIdx.x & 63;
    int row = blockIdx.x * 4 + wave;
    int i1 = idx1[row];
    float iv = invn[row];
    const float4* xr = (const float4*)(x + (size_t)row * D);
    float4 xa = xr[lane], xb = xr[lane + 64];
    const float4* c1 = (const float4*)(cbn + (size_t)i1 * D);
    float4 p = c1[lane], q4 = c1[lane + 64];
    float d1 = xa.x*p.x + xa.y*p.y + xa.z*p.z + xa.w*p.w
             + xb.x*q4.x + xb.y*q4.y + xb.z*q4.z + xb.w*q4.w;
    bool amb = marg[row] < TAU;     // wave-uniform
    int j2 = idx2[row];
    float d2 = 0.f;
    float4 u = {0,0,0,0}, v2 = {0,0,0,0};
    if (amb) {
        const float4* c2 = (const float4*)(cbn + (size_t)j2 * D);
        u = c2[lane]; v2 = c2[lane + 64];
        d2 = xa.x*u.x + xa.y*u.y + xa.z*u.z + xa.w*u.w
           + xb.x*v2.x + xb.y*v2.y + xb.z*v2.z + xb.w*v2.w;
    }
    #pragma unroll
    for (int o = 32; o > 0; o >>= 1) {
        d1 += __shfl_xor(d1, o, 64);
        d2 += __shfl_xor(d2, o, 64);
    }
    float d; float4 s0, s1;
    if (amb) {
        bool take2 = (d2 > d1) || (d2 == d1 && j2 < i1);
        d  = take2 ? d2 : d1;
        s0 = take2 ? u  : p;
        s1 = take2 ? v2 : q4;
    } else {
        d = d1; s0 = p; s1 = q4;
    }
    float mdot = d * iv;
    float4* dst = (float4*)(outq + (size_t)row * D);
    dst[lane]      = s0;
    dst[lane + 64] = s1;
    if (lane == 0) {
        outc[row] = 1.0f - mdot;
        if (marg3[row] < TAU3) {
            pk[row] = 0ULL;
            list[atomicAdd(counter, 1)] = row;
        }
    }
}

// ---------------- Kernel: batched full-codebook rescore (scan phase) -------
__launch_bounds__(256)
__global__ void k_rescore_scan(const float* __restrict__ x,
                               const float* __restrict__ cbn,
                               const int* __restrict__ counter,
                               const int* __restrict__ list,
                               unsigned long long* __restrict__ pk) {
    int cnt = counter[0];
    int tid = threadIdx.x;
    int c = blockIdx.x * 64 + (tid >> 2);
    int seg = tid & 3;                      // 128-dim quarter
    const float4* cr = (const float4*)(cbn + (size_t)c * D) + seg * 32;
    __shared__ float4 xs4[128];
    __shared__ unsigned long long rk[64];
    for (int ii = blockIdx.y; ii < cnt; ii += gridDim.y) {
        int row = list[ii];
        __syncthreads();
        if (tid < 128) xs4[tid] = ((const float4*)(x + (size_t)row * D))[tid];
        __syncthreads();
        const float4* xq = xs4 + seg * 32;
        float da = 0.f, db = 0.f;           // 2 chains halve dep latency
        #pragma unroll 8
        for (int k = 0; k < 32; k += 2) {
            float4 cva = cr[k],     xva = xq[k];
            float4 cvb = cr[k + 1], xvb = xq[k + 1];
            da = fmaf(cva.x, xva.x, da); db = fmaf(cvb.x, xvb.x, db);
            da = fmaf(cva.y, xva.y, da); db = fmaf(cvb.y, xvb.y, db);
            da = fmaf(cva.z, xva.z, da); db = fmaf(cvb.z, xvb.z, db);
            da = fmaf(cva.w, xva.w, da); db = fmaf(cvb.w, xvb.w, db);
        }
        float dot = da + db;
        dot += __shfl_xor(dot, 1, 64);
        dot += __shfl_xor(dot, 2, 64);
        if (seg == 0) {
            unsigned uu = __float_as_uint(dot);
            uu ^= ((unsigned)((int)uu >> 31)) | 0x80000000u;
            rk[tid >> 2] = ((unsigned long long)uu << 32) | (unsigned)(4095 - c);
        }
        __syncthreads();
        if (tid < 32) {
            unsigned long long a = rk[tid], b = rk[tid + 32];
            unsigned long long m = a > b ? a : b;
            #pragma unroll
            for (int o = 16; o > 0; o >>= 1) {
                unsigned long long t = __shfl_down(m, o, 64);
                if (t > m) m = t;
            }
            if (tid == 0) atomicMax(pk + row, m);
        }
    }
}

// ---------------- Kernel: rescore finalize (decode + gather + commit) ------
__global__ void k_rescore_fin(const float* __restrict__ invn,
                              const float* __restrict__ cbn,
                              const int* __restrict__ counter,
                              const int* __restrict__ list,
                              const unsigned long long* __restrict__ pk,
                              float* __restrict__ outq, float* __restrict__ outc) {
    int cnt = counter[0];
    int tid = threadIdx.x;
    for (int ii = blockIdx.x; ii < cnt; ii += gridDim.x) {
        int row = list[ii];
        unsigned long long key = pk[row];
        unsigned ou = (unsigned)(key >> 32);
        int c = 4095 - (int)(key & 0xFFFFFFFFull);
        unsigned mask2 = (ou & 0x80000000u) ? 0x80000000u : 0xFFFFFFFFu;
        float dot = __uint_as_float(ou ^ mask2);
        if (tid < 128)
            ((float4*)(outq + (size_t)row * D))[tid] =
                ((const float4*)(cbn + (size_t)c * D))[tid];
        if (tid == 0) outc[row] = 1.0f - dot * invn[row];
    }
}

// ================= fallback path (f32 VALU, unchanged) ====================
__global__ void k_norm_cb(const float* __restrict__ cb, float* __restrict__ cbn) {
    int row = blockIdx.x;
    const float2* src = (const float2*)(cb + (size_t)row * D);
    float2 v = src[threadIdx.x];
    float ss = v.x * v.x + v.y * v.y;
    #pragma unroll
    for (int o = 32; o > 0; o >>= 1) ss += __shfl_down(ss, o, 64);
    __shared__ float partial[4];
    __shared__ float scale_s;
    if ((threadIdx.x & 63) == 0) partial[threadIdx.x >> 6] = ss;
    __syncthreads();
    if (threadIdx.x == 0) {
        float t = partial[0] + partial[1] + partial[2] + partial[3];
        scale_s = 1.0f / fmaxf(sqrtf(t), 1e-12f);
    }
    __syncthreads();
    float sc = scale_s;
    float2 o2; o2.x = v.x * sc; o2.y = v.y * sc;
    ((float2*)(cbn + (size_t)row * D))[threadIdx.x] = o2;
}

__global__ void k_xnorm(const float* __restrict__ x, float* __restrict__ invn) {
    int wave = threadIdx.x >> 6, lane = threadIdx.x & 63;
    int row = blockIdx.x * 4 + wave;
    const float4* src = (const float4*)(x + (size_t)row * D);
    float4 a = src[lane];
    float4 b = src[lane + 64];
    float ss = a.x*a.x + a.y*a.y + a.z*a.z + a.w*a.w
             + b.x*b.x + b.y*b.y + b.z*b.z + b.w*b.w;
    #pragma unroll
    for (int o = 32; o > 0; o >>= 1) ss += __shfl_down(ss, o, 64);
    if (lane == 0) invn[row] = 1.0f / fmaxf(sqrtf(ss), 1e-12f);
}

#define BN 64
#define BM 64
#define BK 16
#define LSTR 68

__launch_bounds__(256, 2)
__global__ void k_argmax(const float* __restrict__ x, const float* __restrict__ cbn,
                         float* __restrict__ maxdot, int* __restrict__ idxout) {
    __shared__ __align__(16) float xs[BK * LSTR];
    __shared__ __align__(16) float cs[BK * LSTR];
    int tid = threadIdx.x;
    int tx = tid & 15, ty = tid >> 4;
    int qbase = blockIdx.x * BN;
    int sq = tid >> 2;
    int skseg = (tid & 3) * 4;
    const float* xg  = x   + ((size_t)(qbase + sq)) * D + skseg;
    const float* cg0 = cbn + ((size_t)sq) * D + skseg;
    float best[4]; int bidx[4];
    #pragma unroll
    for (int i = 0; i < 4; i++) { best[i] = -1e30f; bidx[i] = 0; }
    for (int mt = 0; mt < M / BM; mt++) {
        float s[4][4] = {};
        const float* cg = cg0 + (size_t)mt * BM * D;
        float4 ax = *(const float4*)(xg);
        float4 ac = *(const float4*)(cg);
        for (int kt = 0; kt < D / BK; kt++) {
            __syncthreads();
            xs[(skseg + 0) * LSTR + sq] = ax.x;
            xs[(skseg + 1) * LSTR + sq] = ax.y;
            xs[(skseg + 2) * LSTR + sq] = ax.z;
            xs[(skseg + 3) * LSTR + sq] = ax.w;
            cs[(skseg + 0) * LSTR + sq] = ac.x;
            cs[(skseg + 1) * LSTR + sq] = ac.y;
            cs[(skseg + 2) * LSTR + sq] = ac.z;
            cs[(skseg + 3) * LSTR + sq] = ac.w;
            if (kt + 1 < D / BK) {
                ax = *(const float4*)(xg + (kt + 1) * BK);
                ac = *(const float4*)(cg + (kt + 1) * BK);
            }
            __syncthreads();
            #pragma unroll
            for (int k = 0; k < BK; k++) {
                float4 a = *(const float4*)&xs[k * LSTR + ty * 4];
                float4 b = *(const float4*)&cs[k * LSTR + tx * 4];
                s[0][0] = fmaf(a.x, b.x, s[0][0]); s[0][1] = fmaf(a.x, b.y, s[0][1]);
                s[0][2] = fmaf(a.x, b.z, s[0][2]); s[0][3] = fmaf(a.x, b.w, s[0][3]);
                s[1][0] = fmaf(a.y, b.x, s[1][0]); s[1][1] = fmaf(a.y, b.y, s[1][1]);
                s[1][2] = fmaf(a.y, b.z, s[1][2]); s[1][3] = fmaf(a.y, b.w, s[1][3]);
                s[2][0] = fmaf(a.z, b.x, s[2][0]); s[2][1] = fmaf(a.z, b.y, s[2][1]);
                s[2][2] = fmaf(a.z, b.z, s[2][2]); s[2][3] = fmaf(a.z, b.w, s[2][3]);
                s[3][0] = fmaf(a.w, b.x, s[3][0]); s[3][1] = fmaf(a.w, b.y, s[3][1]);
                s[3][2] = fmaf(a.w, b.z, s[3][2]); s[3][3] = fmaf(a.w, b.w, s[3][3]);
            }
        }
        #pragma unroll
        for (int i = 0; i < 4; i++) {
            #pragma unroll
            for (int j = 0; j < 4; j++) {
                int ci = mt * BM + tx * 4 + j;
                if (s[i][j] > best[i]) { best[i] = s[i][j]; bidx[i] = ci; }
            }
        }
    }
    __syncthreads();
    float* rv = xs;
    int*   ri = (int*)cs;
    #pragma unroll
    for (int i = 0; i < 4; i++) {
        rv[(ty * 4 + i) * 16 + tx] = best[i];
        ri[(ty * 4 + i) * 16 + tx] = bidx[i];
    }
    __syncthreads();
    if (tid < BN) {
        float bv = rv[tid * 16]; int bb = ri[tid * 16];
        for (int t = 1; t < 16; t++) {
            float v = rv[tid * 16 + t]; int id = ri[tid * 16 + t];
            if (v > bv || (v == bv && id < bb)) { bv = v; bb = id; }
        }
        maxdot[qbase + tid] = bv;
        idxout[qbase + tid] = bb;
    }
}

__global__ void k_write_old(const float* __restrict__ cbn, const int* __restrict__ idx,
                            const float* __restrict__ maxdot, const float* __restrict__ invn,
                            float* __restrict__ outq, float* __restrict__ outc) {
    int wave = threadIdx.x >> 6, lane = threadIdx.x & 63;
    int row = blockIdx.x * 4 + wave;
    int id = idx[row];
    const float4* src = (const float4*)(cbn + (size_t)id * D);
    float4* dst = (float4*)(outq + (size_t)row * D);
    dst[lane]      = src[lane];
    dst[lane + 64] = src[lane + 64];
    if (lane == 0) outc[row] = 1.0f - maxdot[row] * invn[row];
}

// ================= launch =================================================
extern "C" void kernel_launch(void* const* d_in, const int* in_sizes, int n_in,
                              void* d_out, int out_size, void* d_ws, size_t ws_size,
                              hipStream_t stream) {
    const float* x  = (const float*)d_in[0];
    const float* cb = (const float*)d_in[1];
    float* out  = (float*)d_out;
    float* outq = out;
    float* outc = out + (size_t)NQ * D;
    float* cbn  = outc + NQ;

    float* invn    = (float*)d_ws;
    float* margp   = invn + NQ;
    float* marg3p  = margp + NQ;
    float* maxdot  = marg3p + NQ;
    int*   idx     = (int*)(maxdot + NQ);
    int*   idx2    = idx + NQ;
    int*   counter = idx2 + NQ;
    int*   list    = counter + 16;            // pad keeps 8B alignment below
    unsigned long long* pk = (unsigned long long*)(list + NQ);
    float* invcb   = (float*)(pk + NQ);
    _Float16* xhf  = (_Float16*)(invcb + M);
    _Float16* slab = xhf + (size_t)NQ * D;
    size_t needed = (size_t)((char*)(slab + (size_t)M * D) - (char*)d_ws);

    bool fast = ws_size >= needed;

    if (fast) {
        k_prep<<<NQ / 4 + M / 4, 256, 0, stream>>>(x, cb, invn, xhf, invcb, counter);
        k_tile_cb2<<<256, 256, 0, stream>>>(cb, invcb, cbn, slab);
        k_screen_h<<<256, 512, 0, stream>>>(xhf, slab, margp, marg3p, idx, idx2);
        k_write_fix2<<<NQ / 4, 256, 0, stream>>>(x, invn, cbn, margp, marg3p,
                                                 idx, idx2, outq, outc,
                                                 counter, list, pk);
        k_rescore_scan<<<dim3(64, 64), 256, 0, stream>>>(x, cbn, counter, list, pk);
        k_rescore_fin<<<128, 128, 0, stream>>>(invn, cbn, counter, list, pk,
                                               outq, outc);
    } else {
        k_norm_cb<<<M, 256, 0, stream>>>(cb, cbn);
        k_xnorm<<<NQ / 4, 256, 0, stream>>>(x, invn);
        k_argmax<<<NQ / BN, 256, 0, stream>>>(x, cbn, maxdot, idx);
        k_write_old<<<NQ / 4, 256, 0, stream>>>(cbn, idx, maxdot, invn, outq, outc);
    }
}

// Round 9
// 318.746 us; speedup vs baseline: 1.8234x; 1.8234x over previous
//
#include <hip/hip_runtime.h>
#include <stdint.h>

// Problem: x (8,4096,512) f32 -> NQ=32768 rows; codebook (4096,512) f32.
// Outputs f32 concat: q_st[NQ*D], commitment[NQ], cbn[M*D]
//
// v9 = consolidation of measured-best pieces:
//   screen: v5 structure VERBATIM (184.7us measured; 512thr, 128q/block,
//           grid 256, 128KB LDS, dbuf 16KB stages, setprio). Experiments
//           v4 (pipeline 227us), v6/v8 (spill: +32 VGPR over the ~200
//           budget -> scratch, 2.5x loss), v7 (2 blk/CU, 190.6us) all lost.
//   tail:   v7 VERBATIM (143us measured: fused prep, TAU3=1.5e-4 scan gate,
//           block-reduced scan atomics, register-served gather).
// Exactness: marg(s1-s2)<TAU -> exact top-2; marg(s1-s3)<TAU3 -> full scan.
#define NQ 32768
#define D  512
#define M  4096
#define TAU  5e-4f
#define TAU3 1.5e-4f

typedef _Float16 f16x8 __attribute__((ext_vector_type(8)));
typedef _Float16 f16x4 __attribute__((ext_vector_type(4)));
typedef float    f32x16 __attribute__((ext_vector_type(16)));

#define Z16 ((f32x16){0.f,0.f,0.f,0.f,0.f,0.f,0.f,0.f,0.f,0.f,0.f,0.f,0.f,0.f,0.f,0.f})

__device__ __forceinline__ void gl2lds16(const void* g, void* l) {
    __builtin_amdgcn_global_load_lds(
        (const __attribute__((address_space(1))) unsigned int*)g,
        (__attribute__((address_space(3))) unsigned int*)l,
        16, 0, 0);
}

// ---------------- Kernel: fused x-prep + codebook row norms ---------------
__global__ void k_prep(const float* __restrict__ x, const float* __restrict__ cb,
                       float* __restrict__ invn, _Float16* __restrict__ xh,
                       float* __restrict__ invcb, int* __restrict__ counter) {
    int wv = threadIdx.x >> 6, lane = threadIdx.x & 63;
    if (blockIdx.x < NQ / 4) {
        int row = blockIdx.x * 4 + wv;
        const float4* src = (const float4*)(x + (size_t)row * D);
        float4 a = src[lane];
        float4 b = src[lane + 64];
        float ss = a.x*a.x + a.y*a.y + a.z*a.z + a.w*a.w
                 + b.x*b.x + b.y*b.y + b.z*b.z + b.w*b.w;
        #pragma unroll
        for (int o = 32; o > 0; o >>= 1) ss += __shfl_xor(ss, o, 64);
        float iv = 1.0f / fmaxf(sqrtf(ss), 1e-12f);
        if (lane == 0) invn[row] = iv;
        f16x4 ha = { (_Float16)(a.x*iv), (_Float16)(a.y*iv),
                     (_Float16)(a.z*iv), (_Float16)(a.w*iv) };
        f16x4 hb = { (_Float16)(b.x*iv), (_Float16)(b.y*iv),
                     (_Float16)(b.z*iv), (_Float16)(b.w*iv) };
        *(f16x4*)(xh + (size_t)row * D + lane * 4)       = ha;
        *(f16x4*)(xh + (size_t)row * D + 256 + lane * 4) = hb;
    } else {
        if (blockIdx.x == NQ / 4 && threadIdx.x == 0) *counter = 0;
        int row = (blockIdx.x - NQ / 4) * 4 + wv;
        const float4* src = (const float4*)(cb + (size_t)row * D);
        float4 a = src[lane];
        float4 b = src[lane + 64];
        float ss = a.x*a.x + a.y*a.y + a.z*a.z + a.w*a.w
                 + b.x*b.x + b.y*b.y + b.z*b.z + b.w*b.w;
        #pragma unroll
        for (int o = 32; o > 0; o >>= 1) ss += __shfl_xor(ss, o, 64);
        if (lane == 0) invcb[row] = 1.0f / fmaxf(sqrtf(ss), 1e-12f);
    }
}

// ---------------- Kernel: normalize + retile codebook ---------------------
__global__ void k_tile_cb2(const float* __restrict__ cb,
                           const float* __restrict__ invcb,
                           float* __restrict__ cbn,
                           _Float16* __restrict__ slab) {
    int ct = blockIdx.x >> 2, kc = blockIdx.x & 3;   // kc = K-128 quarter
    __shared__ float xs[64 * 129];
    int tid = threadIdx.x;
    #pragma unroll
    for (int pass = 0; pass < 8; pass++) {
        int row = pass * 8 + (tid >> 5);
        int col = (tid & 31) * 4;
        size_t goff = (size_t)(ct * 64 + row) * D + kc * 128 + col;
        float4 v = *(const float4*)(cb + goff);
        float sc = invcb[ct * 64 + row];
        v.x *= sc; v.y *= sc; v.z *= sc; v.w *= sc;
        *(float4*)(cbn + goff) = v;
        xs[row * 129 + col + 0] = v.x;
        xs[row * 129 + col + 1] = v.y;
        xs[row * 129 + col + 2] = v.z;
        xs[row * 129 + col + 3] = v.w;
    }
    __syncthreads();
    #pragma unroll
    for (int i = 0; i < 4; i++) {
        int cid = i * 256 + tid;
        int tt = cid >> 6, m = cid & 63;            // tt: local k-chunk 0..15
        size_t id = (((size_t)ct * 2 + (kc >> 1)) * 32 + (kc & 1) * 16 + tt) * 64 + m;
        f16x8 v;
        #pragma unroll
        for (int j = 0; j < 8; j++) v[j] = (_Float16)xs[m * 129 + tt * 8 + j];
        *(f16x8*)(slab + id * 8) = v;
    }
}

// ---------------- top-3 merge of two sorted triples (idx tiebreak top-2) ---
__device__ __forceinline__ void merge3(float& s1, float& s2, float& s3,
                                       int& i1, int& i2,
                                       float o1, float o2, float o3,
                                       int oi1, int oi2) {
    bool bA = (o1 > s1) || (o1 == s1 && oi1 < i1);
    float m1 = bA ? o1 : s1; int m1i = bA ? oi1 : i1;
    float hAv = bA ? s1 : s2; int hAi = bA ? i1 : i2;
    float hBv = bA ? o2 : o1; int hBi = bA ? oi2 : oi1;
    bool bB = (hBv > hAv) || (hBv == hAv && hBi < hAi);
    float m2 = bB ? hBv : hAv; int m2i = bB ? hBi : hAi;
    float nAv = bA ? s2 : s3;
    float nBv = bA ? o3 : o2;
    float m3 = bB ? fmaxf(hAv, nBv) : fmaxf(hBv, nAv);
    s1 = m1; s2 = m2; s3 = m3; i1 = m1i; i2 = m2i;
}

// ---------------- Kernel: fp16 32x32x16 screen, top-3 (v5, measured) ------
__launch_bounds__(512, 2)
__global__ void k_screen_h(const _Float16* __restrict__ xh_g,
                           const _Float16* __restrict__ slab,
                           float* __restrict__ marg, float* __restrict__ marg3,
                           int* __restrict__ bidx_g, int* __restrict__ bidx2_g) {
    __shared__ f16x8 lbuf[2][2][2048];     // [half][dbuf][t*64+m], 128 KB
    __shared__ float ms1[8][32], ms2[8][32], ms3[8][32];
    __shared__ int   mi1[8][32], mi2[8][32];

    int tid = threadIdx.x;
    int lane = tid & 63, w = tid >> 6;
    int half = w >> 2;                      // code half (0: codes 0..2047)
    int qg = w & 3;                         // query group within block
    int l31 = lane & 31, hi = lane >> 5;
    int q = blockIdx.x * 128 + qg * 32 + l31;

    // pin x fragments: B-frag for 32x32x16: [n=lane&31][k=(lane>>5)*8+j]
    f16x8 xf[32];
    {
        const _Float16* xr = xh_g + (size_t)q * D + hi * 8;
        #pragma unroll
        for (int i = 0; i < 32; i++) xf[i] = *(const f16x8*)(xr + i * 16);
    }

    float s1 = -1e30f, s2 = -1e30f, s3 = -1e30f;
    int i1 = 0, i2 = 0;

    const char* slab_b = (const char*)slab;
    int wl = w & 3;                         // wave index within half

#define STAGE(GSTEP, BUF) do {                                                 \
        const char* sb_ = slab_b + ((size_t)(GSTEP) * 2048 + lane) * 16;       \
        _Pragma("unroll")                                                      \
        for (int i_ = 0; i_ < 8; i_++) {                                       \
            int s_ = wl * 8 + i_;                                              \
            gl2lds16(sb_ + (size_t)s_ * 1024,                                  \
                     (char*)&lbuf[half][BUF][0] + s_ * 1024);                  \
        }                                                                      \
    } while (0)

    // prologue: stage first step of this half into buf0
    STAGE(half * 64, 0);

    for (int ct = 0; ct < 32; ct++) {
        int ctg = half * 32 + ct;
        f32x16 acc0 = Z16, acc1 = Z16;

        // ---- phase kh=0 (K 0..255) ----
        __syncthreads();
        STAGE(ctg * 2 + 1, 1);
        __builtin_amdgcn_s_setprio(1);
        #pragma unroll
        for (int s = 0; s < 16; s++) {
            int cbase = (s * 2 + hi) * 64 + l31;
            f16x8 a0 = lbuf[half][0][cbase];
            f16x8 a1 = lbuf[half][0][cbase + 32];
            acc0 = __builtin_amdgcn_mfma_f32_32x32x16_f16(a0, xf[s], acc0, 0, 0, 0);
            acc1 = __builtin_amdgcn_mfma_f32_32x32x16_f16(a1, xf[s], acc1, 0, 0, 0);
        }
        __builtin_amdgcn_s_setprio(0);
        // ---- phase kh=1 (K 256..511) ----
        __syncthreads();
        if (ct + 1 < 32) STAGE(ctg * 2 + 2, 0);
        __builtin_amdgcn_s_setprio(1);
        #pragma unroll
        for (int s = 0; s < 16; s++) {
            int cbase = (s * 2 + hi) * 64 + l31;
            f16x8 a0 = lbuf[half][1][cbase];
            f16x8 a1 = lbuf[half][1][cbase + 32];
            acc0 = __builtin_amdgcn_mfma_f32_32x32x16_f16(a0, xf[16 + s], acc0, 0, 0, 0);
            acc1 = __builtin_amdgcn_mfma_f32_32x32x16_f16(a1, xf[16 + s], acc1, 0, 0, 0);
        }
        __builtin_amdgcn_s_setprio(0);

        // streaming top-3; within-lane code order ascending -> strict >
        #pragma unroll
        for (int t = 0; t < 2; t++) {
            #pragma unroll
            for (int r = 0; r < 16; r++) {
                float v = t ? acc1[r] : acc0[r];
                int ci = ctg * 64 + t * 32 + (r & 3) + 8 * (r >> 2) + 4 * hi;
                bool b1 = v > s1, b2 = v > s2, b3 = v > s3;
                s3 = b2 ? s2 : (b3 ? v : s3);
                s2 = b1 ? s1 : (b2 ? v : s2);
                i2 = b1 ? i1 : (b2 ? ci : i2);
                s1 = b1 ? v : s1;
                i1 = b1 ? ci : i1;
            }
        }
    }
#undef STAGE

    // merge the two lanes holding the same query (lane ^ 32)
    {
        float o1 = __shfl_xor(s1, 32, 64);
        float o2 = __shfl_xor(s2, 32, 64);
        float o3 = __shfl_xor(s3, 32, 64);
        int oi1 = __shfl_xor(i1, 32, 64);
        int oi2 = __shfl_xor(i2, 32, 64);
        merge3(s1, s2, s3, i1, i2, o1, o2, o3, oi1, oi2);
    }
    if (hi == 0) {
        ms1[w][l31] = s1; ms2[w][l31] = s2; ms3[w][l31] = s3;
        mi1[w][l31] = i1; mi2[w][l31] = i2;
    }
    __syncthreads();
    // merge the two code-halves (waves w and w+4 share a query group)
    if (half == 0 && hi == 0) {
        merge3(s1, s2, s3, i1, i2,
               ms1[w + 4][l31], ms2[w + 4][l31], ms3[w + 4][l31],
               mi1[w + 4][l31], mi2[w + 4][l31]);
        marg[q]    = s1 - s2;
        marg3[q]   = s1 - s3;
        bidx_g[q]  = i1;
        bidx2_g[q] = i2;
    }
}

// ---------------- Kernel: gather + commitment, always-exact dot ------------
__global__ void k_write_fix2(const float* __restrict__ x, const float* __restrict__ invn,
                             const float* __restrict__ cbn,
                             const float* __restrict__ marg, const float* __restrict__ marg3,
                             const int* __restrict__ idx1, const int* __restrict__ idx2,
                             float* __restrict__ outq, float* __restrict__ outc,
                             int* __restrict__ counter, int* __restrict__ list,
                             unsigned long long* __restrict__ pk) {
    int wave = threadIdx.x >> 6, lane = threadIdx.x & 63;
    int row = blockIdx.x * 4 + wave;
    int i1 = idx1[row];
    float iv = invn[row];
    const float4* xr = (const float4*)(x + (size_t)row * D);
    float4 xa = xr[lane], xb = xr[lane + 64];
    const float4* c1 = (const float4*)(cbn + (size_t)i1 * D);
    float4 p = c1[lane], q4 = c1[lane + 64];
    float d1 = xa.x*p.x + xa.y*p.y + xa.z*p.z + xa.w*p.w
             + xb.x*q4.x + xb.y*q4.y + xb.z*q4.z + xb.w*q4.w;
    bool amb = marg[row] < TAU;     // wave-uniform
    int j2 = idx2[row];
    float d2 = 0.f;
    float4 u = {0,0,0,0}, v2 = {0,0,0,0};
    if (amb) {
        const float4* c2 = (const float4*)(cbn + (size_t)j2 * D);
        u = c2[lane]; v2 = c2[lane + 64];
        d2 = xa.x*u.x + xa.y*u.y + xa.z*u.z + xa.w*u.w
           + xb.x*v2.x + xb.y*v2.y + xb.z*v2.z + xb.w*v2.w;
    }
    #pragma unroll
    for (int o = 32; o > 0; o >>= 1) {
        d1 += __shfl_xor(d1, o, 64);
        d2 += __shfl_xor(d2, o, 64);
    }
    float d; float4 s0, s1;
    if (amb) {
        bool take2 = (d2 > d1) || (d2 == d1 && j2 < i1);
        d  = take2 ? d2 : d1;
        s0 = take2 ? u  : p;
        s1 = take2 ? v2 : q4;
    } else {
        d = d1; s0 = p; s1 = q4;
    }
    float mdot = d * iv;
    float4* dst = (float4*)(outq + (size_t)row * D);
    dst[lane]      = s0;
    dst[lane + 64] = s1;
    if (lane == 0) {
        outc[row] = 1.0f - mdot;
        if (marg3[row] < TAU3) {
            pk[row] = 0ULL;
            list[atomicAdd(counter, 1)] = row;
        }
    }
}

// ---------------- Kernel: batched full-codebook rescore (scan phase) -------
__launch_bounds__(256)
__global__ void k_rescore_scan(const float* __restrict__ x,
                               const float* __restrict__ cbn,
                               const int* __restrict__ counter,
                               const int* __restrict__ list,
                               unsigned long long* __restrict__ pk) {
    int cnt = counter[0];
    int tid = threadIdx.x;
    int c = blockIdx.x * 64 + (tid >> 2);
    int seg = tid & 3;                      // 128-dim quarter
    const float4* cr = (const float4*)(cbn + (size_t)c * D) + seg * 32;
    __shared__ float4 xs4[128];
    __shared__ unsigned long long rk[64];
    for (int ii = blockIdx.y; ii < cnt; ii += gridDim.y) {
        int row = list[ii];
        __syncthreads();
        if (tid < 128) xs4[tid] = ((const float4*)(x + (size_t)row * D))[tid];
        __syncthreads();
        const float4* xq = xs4 + seg * 32;
        float da = 0.f, db = 0.f;           // 2 chains halve dep latency
        #pragma unroll 8
        for (int k = 0; k < 32; k += 2) {
            float4 cva = cr[k],     xva = xq[k];
            float4 cvb = cr[k + 1], xvb = xq[k + 1];
            da = fmaf(cva.x, xva.x, da); db = fmaf(cvb.x, xvb.x, db);
            da = fmaf(cva.y, xva.y, da); db = fmaf(cvb.y, xvb.y, db);
            da = fmaf(cva.z, xva.z, da); db = fmaf(cvb.z, xvb.z, db);
            da = fmaf(cva.w, xva.w, da); db = fmaf(cvb.w, xvb.w, db);
        }
        float dot = da + db;
        dot += __shfl_xor(dot, 1, 64);
        dot += __shfl_xor(dot, 2, 64);
        if (seg == 0) {
            unsigned uu = __float_as_uint(dot);
            uu ^= ((unsigned)((int)uu >> 31)) | 0x80000000u;
            rk[tid >> 2] = ((unsigned long long)uu << 32) | (unsigned)(4095 - c);
        }
        __syncthreads();
        if (tid < 32) {
            unsigned long long a = rk[tid], b = rk[tid + 32];
            unsigned long long m = a > b ? a : b;
            #pragma unroll
            for (int o = 16; o > 0; o >>= 1) {
                unsigned long long t = __shfl_down(m, o, 64);
                if (t > m) m = t;
            }
            if (tid == 0) atomicMax(pk + row, m);
        }
    }
}

// ---------------- Kernel: rescore finalize (decode + gather + commit) ------
__global__ void k_rescore_fin(const float* __restrict__ invn,
                              const float* __restrict__ cbn,
                              const int* __restrict__ counter,
                              const int* __restrict__ list,
                              const unsigned long long* __restrict__ pk,
                              float* __restrict__ outq, float* __restrict__ outc) {
    int cnt = counter[0];
    int tid = threadIdx.x;
    for (int ii = blockIdx.x; ii < cnt; ii += gridDim.x) {
        int row = list[ii];
        unsigned long long key = pk[row];
        unsigned ou = (unsigned)(key >> 32);
        int c = 4095 - (int)(key & 0xFFFFFFFFull);
        unsigned mask2 = (ou & 0x80000000u) ? 0x80000000u : 0xFFFFFFFFu;
        float dot = __uint_as_float(ou ^ mask2);
        if (tid < 128)
            ((float4*)(outq + (size_t)row * D))[tid] =
                ((const float4*)(cbn + (size_t)c * D))[tid];
        if (tid == 0) outc[row] = 1.0f - dot * invn[row];
    }
}

// ================= fallback path (f32 VALU, unchanged) ====================
__global__ void k_norm_cb(const float* __restrict__ cb, float* __restrict__ cbn) {
    int row = blockIdx.x;
    const float2* src = (const float2*)(cb + (size_t)row * D);
    float2 v = src[threadIdx.x];
    float ss = v.x * v.x + v.y * v.y;
    #pragma unroll
    for (int o = 32; o > 0; o >>= 1) ss += __shfl_down(ss, o, 64);
    __shared__ float partial[4];
    __shared__ float scale_s;
    if ((threadIdx.x & 63) == 0) partial[threadIdx.x >> 6] = ss;
    __syncthreads();
    if (threadIdx.x == 0) {
        float t = partial[0] + partial[1] + partial[2] + partial[3];
        scale_s = 1.0f / fmaxf(sqrtf(t), 1e-12f);
    }
    __syncthreads();
    float sc = scale_s;
    float2 o2; o2.x = v.x * sc; o2.y = v.y * sc;
    ((float2*)(cbn + (size_t)row * D))[threadIdx.x] = o2;
}

__global__ void k_xnorm(const float* __restrict__ x, float* __restrict__ invn) {
    int wave = threadIdx.x >> 6, lane = threadIdx.x & 63;
    int row = blockIdx.x * 4 + wave;
    const float4* src = (const float4*)(x + (size_t)row * D);
    float4 a = src[lane];
    float4 b = src[lane + 64];
    float ss = a.x*a.x + a.y*a.y + a.z*a.z + a.w*a.w
             + b.x*b.x + b.y*b.y + b.z*b.z + b.w*b.w;
    #pragma unroll
    for (int o = 32; o > 0; o >>= 1) ss += __shfl_down(ss, o, 64);
    if (lane == 0) invn[row] = 1.0f / fmaxf(sqrtf(ss), 1e-12f);
}

#define BN 64
#define BM 64
#define BK 16
#define LSTR 68

__launch_bounds__(256, 2)
__global__ void k_argmax(const float* __restrict__ x, const float* __restrict__ cbn,
                         float* __restrict__ maxdot, int* __restrict__ idxout) {
    __shared__ __align__(16) float xs[BK * LSTR];
    __shared__ __align__(16) float cs[BK * LSTR];
    int tid = threadIdx.x;
    int tx = tid & 15, ty = tid >> 4;
    int qbase = blockIdx.x * BN;
    int sq = tid >> 2;
    int skseg = (tid & 3) * 4;
    const float* xg  = x   + ((size_t)(qbase + sq)) * D + skseg;
    const float* cg0 = cbn + ((size_t)sq) * D + skseg;
    float best[4]; int bidx[4];
    #pragma unroll
    for (int i = 0; i < 4; i++) { best[i] = -1e30f; bidx[i] = 0; }
    for (int mt = 0; mt < M / BM; mt++) {
        float s[4][4] = {};
        const float* cg = cg0 + (size_t)mt * BM * D;
        float4 ax = *(const float4*)(xg);
        float4 ac = *(const float4*)(cg);
        for (int kt = 0; kt < D / BK; kt++) {
            __syncthreads();
            xs[(skseg + 0) * LSTR + sq] = ax.x;
            xs[(skseg + 1) * LSTR + sq] = ax.y;
            xs[(skseg + 2) * LSTR + sq] = ax.z;
            xs[(skseg + 3) * LSTR + sq] = ax.w;
            cs[(skseg + 0) * LSTR + sq] = ac.x;
            cs[(skseg + 1) * LSTR + sq] = ac.y;
            cs[(skseg + 2) * LSTR + sq] = ac.z;
            cs[(skseg + 3) * LSTR + sq] = ac.w;
            if (kt + 1 < D / BK) {
                ax = *(const float4*)(xg + (kt + 1) * BK);
                ac = *(const float4*)(cg + (kt + 1) * BK);
            }
            __syncthreads();
            #pragma unroll
            for (int k = 0; k < BK; k++) {
                float4 a = *(const float4*)&xs[k * LSTR + ty * 4];
                float4 b = *(const float4*)&cs[k * LSTR + tx * 4];
                s[0][0] = fmaf(a.x, b.x, s[0][0]); s[0][1] = fmaf(a.x, b.y, s[0][1]);
                s[0][2] = fmaf(a.x, b.z, s[0][2]); s[0][3] = fmaf(a.x, b.w, s[0][3]);
                s[1][0] = fmaf(a.y, b.x, s[1][0]); s[1][1] = fmaf(a.y, b.y, s[1][1]);
                s[1][2] = fmaf(a.y, b.z, s[1][2]); s[1][3] = fmaf(a.y, b.w, s[1][3]);
                s[2][0] = fmaf(a.z, b.x, s[2][0]); s[2][1] = fmaf(a.z, b.y, s[2][1]);
                s[2][2] = fmaf(a.z, b.z, s[2][2]); s[2][3] = fmaf(a.z, b.w, s[2][3]);
                s[3][0] = fmaf(a.w, b.x, s[3][0]); s[3][1] = fmaf(a.w, b.y, s[3][1]);
                s[3][2] = fmaf(a.w, b.z, s[3][2]); s[3][3] = fmaf(a.w, b.w, s[3][3]);
            }
        }
        #pragma unroll
        for (int i = 0; i < 4; i++) {
            #pragma unroll
            for (int j = 0; j < 4; j++) {
                int ci = mt * BM + tx * 4 + j;
                if (s[i][j] > best[i]) { best[i] = s[i][j]; bidx[i] = ci; }
            }
        }
    }
    __syncthreads();
    float* rv = xs;
    int*   ri = (int*)cs;
    #pragma unroll
    for (int i = 0; i < 4; i++) {
        rv[(ty * 4 + i) * 16 + tx] = best[i];
        ri[(ty * 4 + i) * 16 + tx] = bidx[i];
    }
    __syncthreads();
    if (tid < BN) {
        float bv = rv[tid * 16]; int bb = ri[tid * 16];
        for (int t = 1; t < 16; t++) {
            float v = rv[tid * 16 + t]; int id = ri[tid * 16 + t];
            if (v > bv || (v == bv && id < bb)) { bv = v; bb = id; }
        }
        maxdot[qbase + tid] = bv;
        idxout[qbase + tid] = bb;
    }
}

__global__ void k_write_old(const float* __restrict__ cbn, const int* __restrict__ idx,
                            const float* __restrict__ maxdot, const float* __restrict__ invn,
                            float* __restrict__ outq, float* __restrict__ outc) {
    int wave = threadIdx.x >> 6, lane = threadIdx.x & 63;
    int row = blockIdx.x * 4 + wave;
    int id = idx[row];
    const float4* src = (const float4*)(cbn + (size_t)id * D);
    float4* dst = (float4*)(outq + (size_t)row * D);
    dst[lane]      = src[lane];
    dst[lane + 64] = src[lane + 64];
    if (lane == 0) outc[row] = 1.0f - maxdot[row] * invn[row];
}

// ================= launch =================================================
extern "C" void kernel_launch(void* const* d_in, const int* in_sizes, int n_in,
                              void* d_out, int out_size, void* d_ws, size_t ws_size,
                              hipStream_t stream) {
    const float* x  = (const float*)d_in[0];
    const float* cb = (const float*)d_in[1];
    float* out  = (float*)d_out;
    float* outq = out;
    float* outc = out + (size_t)NQ * D;
    float* cbn  = outc + NQ;

    float* invn    = (float*)d_ws;
    float* margp   = invn + NQ;
    float* marg3p  = margp + NQ;
    float* maxdot  = marg3p + NQ;
    int*   idx     = (int*)(maxdot + NQ);
    int*   idx2    = idx + NQ;
    int*   counter = idx2 + NQ;
    int*   list    = counter + 16;            // pad keeps 8B alignment below
    unsigned long long* pk = (unsigned long long*)(list + NQ);
    float* invcb   = (float*)(pk + NQ);
    _Float16* xhf  = (_Float16*)(invcb + M);
    _Float16* slab = xhf + (size_t)NQ * D;
    size_t needed = (size_t)((char*)(slab + (size_t)M * D) - (char*)d_ws);

    bool fast = ws_size >= needed;

    if (fast) {
        k_prep<<<NQ / 4 + M / 4, 256, 0, stream>>>(x, cb, invn, xhf, invcb, counter);
        k_tile_cb2<<<256, 256, 0, stream>>>(cb, invcb, cbn, slab);
        k_screen_h<<<256, 512, 0, stream>>>(xhf, slab, margp, marg3p, idx, idx2);
        k_write_fix2<<<NQ / 4, 256, 0, stream>>>(x, invn, cbn, margp, marg3p,
                                                 idx, idx2, outq, outc,
                                                 counter, list, pk);
        k_rescore_scan<<<dim3(64, 64), 256, 0, stream>>>(x, cbn, counter, list, pk);
        k_rescore_fin<<<128, 128, 0, stream>>>(invn, cbn, counter, list, pk,
                                               outq, outc);
    } else {
        k_norm_cb<<<M, 256, 0, stream>>>(cb, cbn);
        k_xnorm<<<NQ / 4, 256, 0, stream>>>(x, invn);
        k_argmax<<<NQ / BN, 256, 0, stream>>>(x, cbn, maxdot, idx);
        k_write_old<<<NQ / 4, 256, 0, stream>>>(cbn, idx, maxdot, invn, outq, outc);
    }
}